// Round 12
// baseline (1835.847 us; speedup 1.0000x reference)
//
#include <hip/hip_runtime.h>
#include <hip/hip_bf16.h>
#include <stdint.h>

// Problem sizes (fixed by the reference)
#define IN_F  4096
#define OUT_F 4096
#define NROWS 16384
#define NT    (IN_F / 64)   // 64 K-tiles of BK=64

typedef unsigned short u16;
typedef unsigned int u32;
typedef unsigned long long u64;
typedef __bf16 bf16x8 __attribute__((ext_vector_type(8)));
typedef float  f32x4  __attribute__((ext_vector_type(4)));
typedef u16    u16x8  __attribute__((ext_vector_type(8)));

#define BAR()   asm volatile("s_barrier" ::: "memory")
#define VM8()   asm volatile("s_waitcnt vmcnt(8)" ::: "memory")
#define VM0()   asm volatile("s_waitcnt vmcnt(0)" ::: "memory")

// fp32 -> bf16, round-to-nearest-even (finite inputs only)
__device__ __forceinline__ u16 f2bf(float x) {
    union { float f; uint32_t u; } c; c.f = x;
    uint32_t u = c.u;
    return (u16)((u + 0x7FFFu + ((u >> 16) & 1u)) >> 16);
}

// async global->LDS, 16B per lane. LDS dest = wave-uniform base + lane*16.
__device__ __forceinline__ void gload_lds16(const void* g, void* l) {
    __builtin_amdgcn_global_load_lds(
        (const __attribute__((address_space(1))) void*)g,
        (__attribute__((address_space(3))) void*)l, 16, 0, 0);
}

__device__ __forceinline__ u16 sgn_bf16(float v) {
    return v > 0.f ? 0x3F80 : (v < 0.f ? 0xBF80 : 0);
}

// --- Prep 1 (fast path): per-row alpha = mean(|W|) AND bit-packed signs,
// layout Wbits[kword][row] (kword == K-tile index since BK=64). Bitmap = 2MB,
// L2-resident in every XCD (r4 verified: FETCH 1.16GB -> ~100MB compulsory).
__global__ void prep_wbits_kernel(const float* __restrict__ W,
                                  float* __restrict__ alpha,
                                  u64* __restrict__ Wbits) {
    const int row = blockIdx.x;                       // 0..OUT_F-1
    const int wave = threadIdx.x >> 6, lane = threadIdx.x & 63;
    const float* wr = W + (size_t)row * IN_F;
    float s = 0.f;
#pragma unroll 4
    for (int it = 0; it < 16; ++it) {
        const int kword = it * 4 + wave;              // 64 words per row
        float v = __builtin_nontemporal_load(wr + kword * 64 + lane);
        s += fabsf(v);
        u64 m = __ballot(v > 0.f);                    // 64-bit wave mask
        if (lane == 0) Wbits[(size_t)kword * OUT_F + row] = m;
    }
    for (int off = 32; off > 0; off >>= 1) s += __shfl_down(s, off);
    __shared__ float red[4];
    if (lane == 0) red[wave] = s;
    __syncthreads();
    if (threadIdx.x == 0)
        alpha[row] = (red[0] + red[1] + red[2] + red[3]) * (1.0f / IN_F);
}

// --- Prep 2: x fp32 -> bf16 (RNE), chunk-swizzled for T2 (c8 ^= row&7) ---
__global__ void convx_kernel(const float* __restrict__ X, u16* __restrict__ O,
                             int swz) {
    const size_t idx = (size_t)blockIdx.x * 256 + threadIdx.x; // 16B out chunk
    const int row = (int)(idx >> 9);                 // 512 chunks per row
    const int q = (int)idx & 511;
    const int g = q >> 3, c8 = q & 7;
    const int c8s = swz ? (c8 ^ (row & 7)) : c8;
    const f32x4* src = reinterpret_cast<const f32x4*>(
        X + (size_t)row * IN_F + g * 64 + c8s * 8);
    f32x4 a = __builtin_nontemporal_load(src);
    f32x4 b = __builtin_nontemporal_load(src + 1);
    u16x8 r;
    r[0] = f2bf(a[0]); r[1] = f2bf(a[1]); r[2] = f2bf(a[2]); r[3] = f2bf(a[3]);
    r[4] = f2bf(b[0]); r[5] = f2bf(b[1]); r[6] = f2bf(b[2]); r[7] = f2bf(b[3]);
    reinterpret_cast<u16x8*>(O)[idx] = r;
}

// ============================================================================
// 256x256 GEMM, bit-B round 12: 128x128 PER WAVE (LDS-volume restructure).
// r9-r11 all ~490us: measured 4594 cyc/CU/tile == the 384-b128 LDS-read model
// of 128x64 wave tiles (16 waves x (M+N)=192 rows re-read; A rows read 4x).
// Per-CU LDS volume scales with Sum(M_w+N_w) -- a wave-SHAPE property.
// Change: 1 WG of 256 thr = 4 waves, each 128x128 (wm=wave>>1, wn=wave&1).
// acc[8][8] = 256 regs/lane -> 1 wave/SIMD (launch_bounds(256,1)); total
// ~375 regs < 450 spill line. LDS reads drop to 64 b128/CU/tile (~770 cyc)
// + A-writes ~300 -- all under the per-SIMD MFMA bound (~2400 cyc/tile at
// the 16x16x32 rate). B stays bit->register expansion (r11 math, verified),
// nf 0..7, ping-ponged one cluster ahead so VALU issues under MFMAs.
// Ledger (per wave): prologue [bits(0)x8, A(0)x8, A(1)x8] -> VM8 drains
// bits+A(0), leaves A(1). Tile t issues [bits(t+1)x8 (after last wcur use),
// A(t+2)x8] -> boundary outstanding [A(t+1)8, bits8, A(t+2)8] -> VM8 drains
// A(t+1)+bits(t+1), leaves A(t+2) riding the barrier. Tail t>=NT-2: VM0.
// Hazards: stageA(t+2)->pa2 (ex-A(t-1), last read pre-(t-1)-BAR); no
// ds_writes exist; wcur WAR (reload after last expand) is program-order.
// ============================================================================
__global__ __launch_bounds__(256, 1) void gemm8_kernel(
    const u16* __restrict__ Xbf, const u64* __restrict__ Wbits,
    const float* __restrict__ alpha, const float* __restrict__ bias,
    float* __restrict__ Y) {
    __shared__ u16 Alds[3][16384];   // 96KB: A triple buffer [256 rows][64 k]

    const int tid  = threadIdx.x;
    const int lane = tid & 63, wave = tid >> 6;   // 4 waves
    const int wm = wave >> 1, wn = wave & 1;      // 2(M) x 2(N), 128x128 each
    const int lrow = lane & 15;

    const int wg = blockIdx.x;
    const int i  = wg >> 3;                       // 0..127 within XCD
    const int m0 = (((wg & 7) << 3) | (i >> 4)) << 8;   // xcd*8 + m_local
    const int n0 = (i & 15) << 8;

    // T2 swizzled A ds_read k-offsets (u16 units)
    const int q0 = ((lane >> 4) << 3) ^ ((lrow & 7) << 3);
    const int q1 = q0 ^ 32;
    const int sh = (lane >> 4) << 3;              // bit offset within 32-k half
    const int brow = n0 + wn * 128 + lrow;        // + nf*16 -> lane's B rows

    f32x4 acc[8][8];
#pragma unroll
    for (int a = 0; a < 8; ++a)
#pragma unroll
        for (int b = 0; b < 8; ++b) acc[a][b] = (f32x4){0.f, 0.f, 0.f, 0.f};

    // stage one 128-row half of A K-tile th (4 gload_lds16 / thread @256thr)
    auto stageA = [&](int th, int half, u16* buf) {
        if (th >= NT) return;
#pragma unroll
        for (int j = 0; j < 4; ++j) {
            const int c = half * 1024 + j * 256 + tid;    // 16B chunk idx
            const int row = c >> 3, c8 = c & 7;
            gload_lds16(Xbf + (size_t)(m0 + row) * IN_F + th * 64 + c8 * 8,
                        buf + c * 8);
        }
    };

    u64 wcur[8];
    auto loadbits = [&](int th) {
        if (th >= NT) return;
#pragma unroll
        for (int nf = 0; nf < 8; ++nf)
            wcur[nf] = Wbits[(size_t)th * OUT_F + brow + nf * 16];
    };

    // expand lane's B-frag pair (kk=0,1) for one nf from its 64 sign bits.
    // bit=1 -> +1 (0x3F80), bit=0 -> -1 (0xBF80). r4/r11-verified math.
    auto expand_pair = [&](u64 w, bf16x8* dst) {
        u64 t64 = w >> sh;
        unsigned nb0 = ~(unsigned)t64;            // kk=0 byte at [7:0]
        unsigned nb1 = ~(unsigned)(t64 >> 32);    // kk=1 byte at [7:0]
        union { unsigned u[4]; bf16x8 v; } r0, r1;
#pragma unroll
        for (int e = 0; e < 4; ++e) {
            unsigned s0 = nb0 >> (2 * e), s1 = nb1 >> (2 * e);
            r0.u[e] = 0x3F803F80u | ((s0 & 1u) << 15) | ((s0 & 2u) << 30);
            r1.u[e] = 0x3F803F80u | ((s1 & 1u) << 15) | ((s1 & 2u) << 30);
        }
        dst[0] = r0.v; dst[1] = r1.v;
    };

    // rotating A-buffer pointers: pa0 = A(t), pa1 = A(t+1), pa2 = stage target
    u16* pa0 = &Alds[0][0];
    u16* pa1 = &Alds[1][0];
    u16* pa2 = &Alds[2][0];

    // ---- prologue: bits(0) first, A(0), A(1) -> VM8 drains bits+A(0),
    // leaves A(1)x8 in flight ----
    loadbits(0);
    stageA(0, 0, pa0); stageA(0, 1, pa0);
    stageA(1, 0, pa1); stageA(1, 1, pa1);
    VM8(); BAR();

    for (int t = 0; t < NT; ++t) {
        const u16* Ar = pa0 + wm * 8192 + lrow * 64;
        bf16x8 af0[8], af1[8];
#pragma unroll
        for (int mm = 0; mm < 8; ++mm) {
            af0[mm] = *reinterpret_cast<const bf16x8*>(Ar + mm * 1024 + q0);
            af1[mm] = *reinterpret_cast<const bf16x8*>(Ar + mm * 1024 + q1);
        }

        // ping-pong B frags: expand nf+1 ahead of nf's MFMA cluster
        bf16x8 bb[2][2];
        expand_pair(wcur[0], bb[0]);
#pragma unroll
        for (int nf = 0; nf < 8; ++nf) {
            if (nf < 7) expand_pair(wcur[nf + 1], bb[(nf + 1) & 1]);
            __builtin_amdgcn_s_setprio(1);
#pragma unroll
            for (int mm = 0; mm < 8; ++mm) {
                acc[mm][nf] = __builtin_amdgcn_mfma_f32_16x16x32_bf16(af0[mm], bb[nf & 1][0], acc[mm][nf], 0, 0, 0);
                acc[mm][nf] = __builtin_amdgcn_mfma_f32_16x16x32_bf16(af1[mm], bb[nf & 1][1], acc[mm][nf], 0, 0, 0);
            }
            __builtin_amdgcn_s_setprio(0);
        }

        // issue next-tile loads: bits(t+1) BEFORE A(t+2) (ledger order)
        loadbits(t + 1);
        stageA(t + 2, 0, pa2); stageA(t + 2, 1, pa2);

        if (t >= NT - 2) { VM0(); } else { VM8(); }
        BAR();

        u16* tp = pa0; pa0 = pa1; pa1 = pa2; pa2 = tp;
    }

    // epilogue: y = acc*alpha[col] + bias[col]; C/D: col=lane&15, row=(lane>>4)*4+r
#pragma unroll
    for (int nf = 0; nf < 8; ++nf) {
        const int col = n0 + wn * 128 + nf * 16 + lrow;
        const float al = alpha[col], bi = bias[col];
#pragma unroll
        for (int mf = 0; mf < 8; ++mf) {
            const int rbase = m0 + wm * 128 + mf * 16 + ((lane >> 4) << 2);
#pragma unroll
            for (int r = 0; r < 4; ++r)
                __builtin_nontemporal_store(acc[mf][nf][r] * al + bi,
                    &Y[(size_t)(rbase + r) * OUT_F + col]);
        }
    }
}

// ============================================================================
// Fallback (small workspace): round-1 128x128 kernel, A reg-staged from fp32,
// bf16 Wsign unswizzled. Verified correct in round 1.
// ============================================================================
__global__ void prep_w_kernel(const float* __restrict__ W,
                              float* __restrict__ alpha,
                              u16* __restrict__ S) {
    const int row = blockIdx.x;
    const float* wr = W + (size_t)row * IN_F;
    float s = 0.f;
    for (int c = threadIdx.x; c < 512; c += 256) {
        const f32x4* src = reinterpret_cast<const f32x4*>(wr + c * 8);
        f32x4 v0 = __builtin_nontemporal_load(src);
        f32x4 v1 = __builtin_nontemporal_load(src + 1);
        s += fabsf(v0[0]) + fabsf(v0[1]) + fabsf(v0[2]) + fabsf(v0[3])
           + fabsf(v1[0]) + fabsf(v1[1]) + fabsf(v1[2]) + fabsf(v1[3]);
        u16x8 r;
        r[0] = sgn_bf16(v0[0]); r[1] = sgn_bf16(v0[1]);
        r[2] = sgn_bf16(v0[2]); r[3] = sgn_bf16(v0[3]);
        r[4] = sgn_bf16(v1[0]); r[5] = sgn_bf16(v1[1]);
        r[6] = sgn_bf16(v1[2]); r[7] = sgn_bf16(v1[3]);
        *reinterpret_cast<u16x8*>(S + (size_t)row * IN_F + c * 8) = r;
    }
    for (int off = 32; off > 0; off >>= 1) s += __shfl_down(s, off);
    __shared__ float red[4];
    const int wave = threadIdx.x >> 6, lane = threadIdx.x & 63;
    if (lane == 0) red[wave] = s;
    __syncthreads();
    if (threadIdx.x == 0)
        alpha[row] = (red[0] + red[1] + red[2] + red[3]) * (1.0f / IN_F);
}

__global__ __launch_bounds__(256) void gemm_fallback(
    const float* __restrict__ X, const u16* __restrict__ Wsign,
    const float* __restrict__ alpha, const float* __restrict__ bias,
    float* __restrict__ Y) {
    __shared__ u16 Axl[128 * 64];
    __shared__ u16 Bxl[128 * 64];

    const int tid = threadIdx.x;
    const int n0 = blockIdx.x * 128;
    const int m0 = blockIdx.y * 128;
    const int wave = tid >> 6, lane = tid & 63;
    const int wm = wave >> 1, wn = wave & 1;
    const int lrow = lane & 15;
    const int lk8 = (lane >> 4) * 8;

    f32x4 acc[4][4];
#pragma unroll
    for (int a = 0; a < 4; ++a)
#pragma unroll
        for (int b = 0; b < 4; ++b) acc[a][b] = (f32x4){0.f, 0.f, 0.f, 0.f};

    for (int kt = 0; kt < IN_F; kt += 64) {
#pragma unroll
        for (int j = 0; j < 4; ++j) {
            const int idx = j * 256 + tid;
            const int row = idx >> 3, c8 = idx & 7;
            gload_lds16(Wsign + (size_t)(n0 + row) * IN_F + kt + c8 * 8,
                        &Bxl[idx * 8]);
        }
#pragma unroll
        for (int j = 0; j < 4; ++j) {
            const int idx = j * 256 + tid;
            const int row = idx >> 3, c8 = idx & 7;
            const float* src = X + (size_t)(m0 + row) * IN_F + kt + c8 * 8;
            float4 v0 = *reinterpret_cast<const float4*>(src);
            float4 v1 = *reinterpret_cast<const float4*>(src + 4);
            u16x8 r;
            r[0] = f2bf(v0.x); r[1] = f2bf(v0.y); r[2] = f2bf(v0.z); r[3] = f2bf(v0.w);
            r[4] = f2bf(v1.x); r[5] = f2bf(v1.y); r[6] = f2bf(v1.z); r[7] = f2bf(v1.w);
            *reinterpret_cast<u16x8*>(&Axl[idx * 8]) = r;
        }
        __syncthreads();
#pragma unroll
        for (int kk = 0; kk < 2; ++kk) {
            bf16x8 af[4], bfv[4];
#pragma unroll
            for (int mf = 0; mf < 4; ++mf)
                af[mf] = *reinterpret_cast<const bf16x8*>(
                    &Axl[(wm * 64 + mf * 16 + lrow) * 64 + kk * 32 + lk8]);
#pragma unroll
            for (int nf = 0; nf < 4; ++nf)
                bfv[nf] = *reinterpret_cast<const bf16x8*>(
                    &Bxl[(wn * 64 + nf * 16 + lrow) * 64 + kk * 32 + lk8]);
#pragma unroll
            for (int mf = 0; mf < 4; ++mf)
#pragma unroll
                for (int nf = 0; nf < 4; ++nf)
                    acc[mf][nf] = __builtin_amdgcn_mfma_f32_16x16x32_bf16(
                        af[mf], bfv[nf], acc[mf][nf], 0, 0, 0);
        }
        __syncthreads();
    }
#pragma unroll
    for (int nf = 0; nf < 4; ++nf) {
        const int col = n0 + wn * 64 + nf * 16 + lrow;
        const float al = alpha[col], bi = bias[col];
#pragma unroll
        for (int mf = 0; mf < 4; ++mf) {
            const int rbase = m0 + wm * 64 + mf * 16 + (lane >> 4) * 4;
#pragma unroll
            for (int r = 0; r < 4; ++r)
                __builtin_nontemporal_store(acc[mf][nf][r] * al + bi,
                    &Y[(size_t)(rbase + r) * OUT_F + col]);
        }
    }
}

extern "C" void kernel_launch(void* const* d_in, const int* in_sizes, int n_in,
                              void* d_out, int out_size, void* d_ws, size_t ws_size,
                              hipStream_t stream) {
    const float* X    = (const float*)d_in[0];
    const float* W    = (const float*)d_in[1];
    const float* bias = (const float*)d_in[2];
    float* Y = (float*)d_out;

    char* ws = (char*)d_ws;
    float* alpha = (float*)ws;                               // 16 KB
    const size_t WBITS_OFF = 16384;
    const size_t XBF_OFF   = WBITS_OFF + (size_t)OUT_F * (IN_F / 8); // +2 MB
    const size_t need_fast = XBF_OFF + (size_t)NROWS * IN_F * 2;     // +128 MB

    if (ws_size >= need_fast) {
        u64* Wbits = (u64*)(ws + WBITS_OFF);
        u16* Xbf   = (u16*)(ws + XBF_OFF);
        prep_wbits_kernel<<<OUT_F, 256, 0, stream>>>(W, alpha, Wbits);
        convx_kernel<<<(size_t)NROWS * IN_F / 8 / 256, 256, 0, stream>>>(X, Xbf, 1);
        gemm8_kernel<<<dim3(1024), 256, 0, stream>>>(Xbf, Wbits, alpha, bias, Y);
    } else {
        u16* Wsign = (u16*)(ws + 16384);
        prep_w_kernel<<<OUT_F, 256, 0, stream>>>(W, alpha, Wsign);
        dim3 grid(OUT_F / 128, NROWS / 128);
        gemm_fallback<<<grid, 256, 0, stream>>>(X, Wsign, alpha, bias, Y);
    }
}

// Round 13
// 556.896 us; speedup vs baseline: 3.2966x; 3.2966x over previous
//
#include <hip/hip_runtime.h>
#include <hip/hip_bf16.h>
#include <stdint.h>

// Problem sizes (fixed by the reference)
#define IN_F  4096
#define OUT_F 4096
#define NROWS 16384
#define NT    (IN_F / 64)   // 64 K-tiles of BK=64

typedef unsigned short u16;
typedef unsigned int u32;
typedef unsigned long long u64;
typedef __bf16 bf16x8 __attribute__((ext_vector_type(8)));
typedef float  f32x4  __attribute__((ext_vector_type(4)));
typedef float  f32x16 __attribute__((ext_vector_type(16)));
typedef u16    u16x8  __attribute__((ext_vector_type(8)));

#define BAR()   asm volatile("s_barrier" ::: "memory")
#define VM4()   asm volatile("s_waitcnt vmcnt(4)" ::: "memory")
#define VM0()   asm volatile("s_waitcnt vmcnt(0)" ::: "memory")

// fp32 -> bf16, round-to-nearest-even (finite inputs only)
__device__ __forceinline__ u16 f2bf(float x) {
    union { float f; uint32_t u; } c; c.f = x;
    uint32_t u = c.u;
    return (u16)((u + 0x7FFFu + ((u >> 16) & 1u)) >> 16);
}

// async global->LDS, 16B per lane. LDS dest = wave-uniform base + lane*16.
__device__ __forceinline__ void gload_lds16(const void* g, void* l) {
    __builtin_amdgcn_global_load_lds(
        (const __attribute__((address_space(1))) void*)g,
        (__attribute__((address_space(3))) void*)l, 16, 0, 0);
}

__device__ __forceinline__ u16 sgn_bf16(float v) {
    return v > 0.f ? 0x3F80 : (v < 0.f ? 0xBF80 : 0);
}

// --- Prep 1 (fast path): per-row alpha = mean(|W|) AND bit-packed signs,
// layout Wbits[kword][row] (kword == K-tile index since BK=64). Bitmap = 2MB,
// L2-resident in every XCD (r4 verified: FETCH 1.16GB -> ~100MB compulsory).
__global__ void prep_wbits_kernel(const float* __restrict__ W,
                                  float* __restrict__ alpha,
                                  u64* __restrict__ Wbits) {
    const int row = blockIdx.x;                       // 0..OUT_F-1
    const int wave = threadIdx.x >> 6, lane = threadIdx.x & 63;
    const float* wr = W + (size_t)row * IN_F;
    float s = 0.f;
#pragma unroll 4
    for (int it = 0; it < 16; ++it) {
        const int kword = it * 4 + wave;              // 64 words per row
        float v = __builtin_nontemporal_load(wr + kword * 64 + lane);
        s += fabsf(v);
        u64 m = __ballot(v > 0.f);                    // 64-bit wave mask
        if (lane == 0) Wbits[(size_t)kword * OUT_F + row] = m;
    }
    for (int off = 32; off > 0; off >>= 1) s += __shfl_down(s, off);
    __shared__ float red[4];
    if (lane == 0) red[wave] = s;
    __syncthreads();
    if (threadIdx.x == 0)
        alpha[row] = (red[0] + red[1] + red[2] + red[3]) * (1.0f / IN_F);
}

// --- Prep 2: x fp32 -> bf16 (RNE), chunk-swizzled for T2 (c8 ^= row&7) ---
__global__ void convx_kernel(const float* __restrict__ X, u16* __restrict__ O,
                             int swz) {
    const size_t idx = (size_t)blockIdx.x * 256 + threadIdx.x; // 16B out chunk
    const int row = (int)(idx >> 9);                 // 512 chunks per row
    const int q = (int)idx & 511;
    const int g = q >> 3, c8 = q & 7;
    const int c8s = swz ? (c8 ^ (row & 7)) : c8;
    const f32x4* src = reinterpret_cast<const f32x4*>(
        X + (size_t)row * IN_F + g * 64 + c8s * 8);
    f32x4 a = __builtin_nontemporal_load(src);
    f32x4 b = __builtin_nontemporal_load(src + 1);
    u16x8 r;
    r[0] = f2bf(a[0]); r[1] = f2bf(a[1]); r[2] = f2bf(a[2]); r[3] = f2bf(a[3]);
    r[4] = f2bf(b[0]); r[5] = f2bf(b[1]); r[6] = f2bf(b[2]); r[7] = f2bf(b[3]);
    reinterpret_cast<u16x8*>(O)[idx] = r;
}

// ============================================================================
// 256x256 GEMM, bit-B round 13: 32x32x16 MFMA (r11 structure, bigger MFMA).
// r12 post-mortem: acc[8][8] -> 256 VGPR -> 1 wave/SIMD -> 12% util; reverted
// to r11's 8-wave/128x64-per-wave shape (2 waves/SIMD, proven no-spill).
// r9-r11 pinned at 490us = 54% of the 16x16x32 pipe (2075 TF). Change: use
// mfma_f32_32x32x16_bf16 -- pipe ceiling 2382 TF (floor 265->231us) and HALF
// the MFMA instructions (32/wave/tile vs 64): less issue/dep pressure.
// Frags: A row=lane&31, k=(lane>>5)*8+e (generalizes the verified 16x16
// pattern); B col=lane&31 same k; C/D col=lane&31, row=(r&3)+8*(r>>2)+
// 4*(lane>>5) [guide m74/m101-verified]. Per wave tile 128x64: mm=4 (32-row),
// nf=2 (32-col), kk=4 (K16). B expansion re-indexes byte select only:
// byte = bits >> (kk*16 + grp*8). A ds_read swizzle c8=(kk*2+grp)^(lane&7)
// -- same balanced bank pattern as r11 (8 accesses/bank over 8 clks).
// Ledger: 6 loads/tile (bits(t+1)x2 then A(t+2)x4). Boundary outstanding
// [A(t+1)x4, bits(t+1)x2, A(t+2)x4]=10 -> VM4 drains A(t+1)+bits, leaves
// A(t+2)x4. Prologue [bits0x2,A0x4,A1x4]=10 -> VM4 drains bits0+A0. Tail
// t>=NT-2 -> VM0. One BAR/tile (r9-proven hazard audit: A triple-buffered,
// no ds_writes, wcur WAR in program order).
// ============================================================================
__global__ __launch_bounds__(512, 2) void gemm8_kernel(
    const u16* __restrict__ Xbf, const u64* __restrict__ Wbits,
    const float* __restrict__ alpha, const float* __restrict__ bias,
    float* __restrict__ Y) {
    __shared__ u16 Alds[3][16384];   // 96KB: A triple buffer [256 rows][64 k]

    const int tid  = threadIdx.x;
    const int lane = tid & 63, wave = tid >> 6;
    const int wm = wave >> 2, wn = wave & 3;      // 2(M) x 4(N) waves
    const int l31 = lane & 31, grp = lane >> 5;   // 32x32 frag row/col, k-group

    const int wg = blockIdx.x;
    const int i  = wg >> 3;                       // 0..127 within XCD
    const int m0 = (((wg & 7) << 3) | (i >> 4)) << 8;   // xcd*8 + m_local
    const int n0 = (i & 15) << 8;

    const int l7 = lane & 7;                      // = arow&7 (rows are +32*mm)

    f32x16 acc[4][2];
#pragma unroll
    for (int a = 0; a < 4; ++a)
#pragma unroll
        for (int b = 0; b < 2; ++b)
#pragma unroll
            for (int e = 0; e < 16; ++e) acc[a][b][e] = 0.f;

    // stage one 128-row half of A K-tile th (2 gload_lds16 / thread @512thr)
    auto stageA = [&](int th, int half, u16* buf) {
        if (th >= NT) return;
#pragma unroll
        for (int t2 = 0; t2 < 2; ++t2) {
            const int c = half * 1024 + t2 * 512 + tid;   // 16B chunk idx
            const int row = c >> 3, c8 = c & 7;
            gload_lds16(Xbf + (size_t)(m0 + row) * IN_F + th * 64 + c8 * 8,
                        buf + c * 8);
        }
    };

    u64 wcur[2];
    auto loadbits = [&](int th) {
        if (th >= NT) return;
#pragma unroll
        for (int nf = 0; nf < 2; ++nf)
            wcur[nf] = Wbits[(size_t)th * OUT_F + n0 + wn * 64 + nf * 32 + l31];
    };

    // expand lane's 8 sign bits for k-step kk (16 k, this lane's 8) -> bf16x8.
    // bit=1 -> +1 (0x3F80), bit=0 -> -1 (0xBF80). r4/r11-verified bit math,
    // re-indexed: byte = bits >> (kk*16 + grp*8).
    auto expand8 = [&](u64 w, int kk) -> bf16x8 {
        unsigned nb = ~(unsigned)(w >> (kk * 16 + grp * 8));
        union { unsigned u[4]; bf16x8 v; } r;
#pragma unroll
        for (int e = 0; e < 4; ++e) {
            unsigned s = nb >> (2 * e);
            r.u[e] = 0x3F803F80u | ((s & 1u) << 15) | ((s & 2u) << 30);
        }
        return r.v;
    };

    // rotating A-buffer pointers: pa0 = A(t), pa1 = A(t+1), pa2 = stage target
    u16* pa0 = &Alds[0][0];
    u16* pa1 = &Alds[1][0];
    u16* pa2 = &Alds[2][0];

    // ---- prologue: bits(0), A(0), A(1) -> VM4 drains bits0+A(0),
    // leaves A(1)x4 in flight (steady-state invariant) ----
    loadbits(0);
    stageA(0, 0, pa0); stageA(0, 1, pa0);
    stageA(1, 0, pa1); stageA(1, 1, pa1);
    VM4(); BAR();

    for (int t = 0; t < NT; ++t) {
        // lane's A base: row = wm*128 + mm*32 + l31, row-major [256][64] u16,
        // chunk swizzle c8 = (kk*2 + grp) ^ l7
        const u16* Ar = pa0 + (wm * 128 + l31) * 64;

        bf16x8 afP[4], afQ[4];
#pragma unroll
        for (int mm = 0; mm < 4; ++mm)
            afP[mm] = *reinterpret_cast<const bf16x8*>(
                Ar + mm * 2048 + ((grp ^ l7) << 3));           // kk=0

#pragma unroll
        for (int kk = 0; kk < 4; ++kk) {
            if (kk < 3) {
                const int c8n = ((kk + 1) * 2 + grp) ^ l7;
#pragma unroll
                for (int mm = 0; mm < 4; ++mm)
                    afQ[mm] = *reinterpret_cast<const bf16x8*>(
                        Ar + mm * 2048 + (c8n << 3));
            }
            bf16x8 b0 = expand8(wcur[0], kk);
            bf16x8 b1 = expand8(wcur[1], kk);
            __builtin_amdgcn_s_setprio(1);
#pragma unroll
            for (int mm = 0; mm < 4; ++mm) {
                acc[mm][0] = __builtin_amdgcn_mfma_f32_32x32x16_bf16(afP[mm], b0, acc[mm][0], 0, 0, 0);
                acc[mm][1] = __builtin_amdgcn_mfma_f32_32x32x16_bf16(afP[mm], b1, acc[mm][1], 0, 0, 0);
            }
            __builtin_amdgcn_s_setprio(0);
#pragma unroll
            for (int mm = 0; mm < 4; ++mm) afP[mm] = afQ[mm];
        }

        // issue next-tile loads: bits(t+1) BEFORE A(t+2) (ledger order);
        // wcur WAR is program-order (last expand above precedes reload)
        loadbits(t + 1);
        stageA(t + 2, 0, pa2); stageA(t + 2, 1, pa2);

        if (t >= NT - 2) { VM0(); } else { VM4(); }
        BAR();

        u16* tp = pa0; pa0 = pa1; pa1 = pa2; pa2 = tp;
    }

    // epilogue: y = acc*alpha[col] + bias[col]
    // 32x32 C/D (m74/m101): col = lane&31, row = (r&3) + 8*(r>>2) + 4*grp
#pragma unroll
    for (int nf = 0; nf < 2; ++nf) {
        const int col = n0 + wn * 64 + nf * 32 + l31;
        const float al = alpha[col], bi = bias[col];
#pragma unroll
        for (int mm = 0; mm < 4; ++mm) {
            const int rb = m0 + wm * 128 + mm * 32 + (grp << 2);
#pragma unroll
            for (int r = 0; r < 16; ++r) {
                const int row = rb + (r & 3) + ((r >> 2) << 3);
                __builtin_nontemporal_store(acc[mm][nf][r] * al + bi,
                    &Y[(size_t)row * OUT_F + col]);
            }
        }
    }
}

// ============================================================================
// Fallback (small workspace): round-1 128x128 kernel, A reg-staged from fp32,
// bf16 Wsign unswizzled. Verified correct in round 1.
// ============================================================================
__global__ void prep_w_kernel(const float* __restrict__ W,
                              float* __restrict__ alpha,
                              u16* __restrict__ S) {
    const int row = blockIdx.x;
    const float* wr = W + (size_t)row * IN_F;
    float s = 0.f;
    for (int c = threadIdx.x; c < 512; c += 256) {
        const f32x4* src = reinterpret_cast<const f32x4*>(wr + c * 8);
        f32x4 v0 = __builtin_nontemporal_load(src);
        f32x4 v1 = __builtin_nontemporal_load(src + 1);
        s += fabsf(v0[0]) + fabsf(v0[1]) + fabsf(v0[2]) + fabsf(v0[3])
           + fabsf(v1[0]) + fabsf(v1[1]) + fabsf(v1[2]) + fabsf(v1[3]);
        u16x8 r;
        r[0] = sgn_bf16(v0[0]); r[1] = sgn_bf16(v0[1]);
        r[2] = sgn_bf16(v0[2]); r[3] = sgn_bf16(v0[3]);
        r[4] = sgn_bf16(v1[0]); r[5] = sgn_bf16(v1[1]);
        r[6] = sgn_bf16(v1[2]); r[7] = sgn_bf16(v1[3]);
        *reinterpret_cast<u16x8*>(S + (size_t)row * IN_F + c * 8) = r;
    }
    for (int off = 32; off > 0; off >>= 1) s += __shfl_down(s, off);
    __shared__ float red[4];
    const int wave = threadIdx.x >> 6, lane = threadIdx.x & 63;
    if (lane == 0) red[wave] = s;
    __syncthreads();
    if (threadIdx.x == 0)
        alpha[row] = (red[0] + red[1] + red[2] + red[3]) * (1.0f / IN_F);
}

__global__ __launch_bounds__(256) void gemm_fallback(
    const float* __restrict__ X, const u16* __restrict__ Wsign,
    const float* __restrict__ alpha, const float* __restrict__ bias,
    float* __restrict__ Y) {
    __shared__ u16 Axl[128 * 64];
    __shared__ u16 Bxl[128 * 64];

    const int tid = threadIdx.x;
    const int n0 = blockIdx.x * 128;
    const int m0 = blockIdx.y * 128;
    const int wave = tid >> 6, lane = tid & 63;
    const int wm = wave >> 1, wn = wave & 1;
    const int lrow = lane & 15;
    const int lk8 = (lane >> 4) * 8;

    f32x4 acc[4][4];
#pragma unroll
    for (int a = 0; a < 4; ++a)
#pragma unroll
        for (int b = 0; b < 4; ++b) acc[a][b] = (f32x4){0.f, 0.f, 0.f, 0.f};

    for (int kt = 0; kt < IN_F; kt += 64) {
#pragma unroll
        for (int j = 0; j < 4; ++j) {
            const int idx = j * 256 + tid;
            const int row = idx >> 3, c8 = idx & 7;
            gload_lds16(Wsign + (size_t)(n0 + row) * IN_F + kt + c8 * 8,
                        &Bxl[idx * 8]);
        }
#pragma unroll
        for (int j = 0; j < 4; ++j) {
            const int idx = j * 256 + tid;
            const int row = idx >> 3, c8 = idx & 7;
            const float* src = X + (size_t)(m0 + row) * IN_F + kt + c8 * 8;
            float4 v0 = *reinterpret_cast<const float4*>(src);
            float4 v1 = *reinterpret_cast<const float4*>(src + 4);
            u16x8 r;
            r[0] = f2bf(v0.x); r[1] = f2bf(v0.y); r[2] = f2bf(v0.z); r[3] = f2bf(v0.w);
            r[4] = f2bf(v1.x); r[5] = f2bf(v1.y); r[6] = f2bf(v1.z); r[7] = f2bf(v1.w);
            *reinterpret_cast<u16x8*>(&Axl[idx * 8]) = r;
        }
        __syncthreads();
#pragma unroll
        for (int kk = 0; kk < 2; ++kk) {
            bf16x8 af[4], bfv[4];
#pragma unroll
            for (int mf = 0; mf < 4; ++mf)
                af[mf] = *reinterpret_cast<const bf16x8*>(
                    &Axl[(wm * 64 + mf * 16 + lrow) * 64 + kk * 32 + lk8]);
#pragma unroll
            for (int nf = 0; nf < 4; ++nf)
                bfv[nf] = *reinterpret_cast<const bf16x8*>(
                    &Bxl[(wn * 64 + nf * 16 + lrow) * 64 + kk * 32 + lk8]);
#pragma unroll
            for (int mf = 0; mf < 4; ++mf)
#pragma unroll
                for (int nf = 0; nf < 4; ++nf)
                    acc[mf][nf] = __builtin_amdgcn_mfma_f32_16x16x32_bf16(
                        af[mf], bfv[nf], acc[mf][nf], 0, 0, 0);
        }
        __syncthreads();
    }
#pragma unroll
    for (int nf = 0; nf < 4; ++nf) {
        const int col = n0 + wn * 64 + nf * 16 + lrow;
        const float al = alpha[col], bi = bias[col];
#pragma unroll
        for (int mf = 0; mf < 4; ++mf) {
            const int rbase = m0 + wm * 64 + mf * 16 + (lane >> 4) * 4;
#pragma unroll
            for (int r = 0; r < 4; ++r)
                __builtin_nontemporal_store(acc[mf][nf][r] * al + bi,
                    &Y[(size_t)(rbase + r) * OUT_F + col]);
        }
    }
}

extern "C" void kernel_launch(void* const* d_in, const int* in_sizes, int n_in,
                              void* d_out, int out_size, void* d_ws, size_t ws_size,
                              hipStream_t stream) {
    const float* X    = (const float*)d_in[0];
    const float* W    = (const float*)d_in[1];
    const float* bias = (const float*)d_in[2];
    float* Y = (float*)d_out;

    char* ws = (char*)d_ws;
    float* alpha = (float*)ws;                               // 16 KB
    const size_t WBITS_OFF = 16384;
    const size_t XBF_OFF   = WBITS_OFF + (size_t)OUT_F * (IN_F / 8); // +2 MB
    const size_t need_fast = XBF_OFF + (size_t)NROWS * IN_F * 2;     // +128 MB

    if (ws_size >= need_fast) {
        u64* Wbits = (u64*)(ws + WBITS_OFF);
        u16* Xbf   = (u16*)(ws + XBF_OFF);
        prep_wbits_kernel<<<OUT_F, 256, 0, stream>>>(W, alpha, Wbits);
        convx_kernel<<<(size_t)NROWS * IN_F / 8 / 256, 256, 0, stream>>>(X, Xbf, 1);
        gemm8_kernel<<<dim3(1024), 512, 0, stream>>>(Xbf, Wbits, alpha, bias, Y);
    } else {
        u16* Wsign = (u16*)(ws + 16384);
        prep_w_kernel<<<OUT_F, 256, 0, stream>>>(W, alpha, Wsign);
        dim3 grid(OUT_F / 128, NROWS / 128);
        gemm_fallback<<<grid, 256, 0, stream>>>(X, Wsign, alpha, bias, Y);
    }
}

// Round 14
// 521.025 us; speedup vs baseline: 3.5235x; 1.0688x over previous
//
#include <hip/hip_runtime.h>
#include <hip/hip_bf16.h>
#include <stdint.h>

// Problem sizes (fixed by the reference)
#define IN_F  4096
#define OUT_F 4096
#define NROWS 16384
#define NT    (IN_F / 64)   // 64 K-tiles of BK=64

typedef unsigned short u16;
typedef unsigned int u32;
typedef unsigned long long u64;
typedef __bf16 bf16x8 __attribute__((ext_vector_type(8)));
typedef float  f32x4  __attribute__((ext_vector_type(4)));
typedef u16    u16x8  __attribute__((ext_vector_type(8)));

#define BAR()   asm volatile("s_barrier" ::: "memory")
#define VM8()   asm volatile("s_waitcnt vmcnt(8)" ::: "memory")
#define VM4()   asm volatile("s_waitcnt vmcnt(4)" ::: "memory")
#define VM0()   asm volatile("s_waitcnt vmcnt(0)" ::: "memory")

// fp32 -> bf16, round-to-nearest-even (finite inputs only)
__device__ __forceinline__ u16 f2bf(float x) {
    union { float f; uint32_t u; } c; c.f = x;
    uint32_t u = c.u;
    return (u16)((u + 0x7FFFu + ((u >> 16) & 1u)) >> 16);
}

// async global->LDS, 16B per lane. LDS dest = wave-uniform base + lane*16.
__device__ __forceinline__ void gload_lds16(const void* g, void* l) {
    __builtin_amdgcn_global_load_lds(
        (const __attribute__((address_space(1))) void*)g,
        (__attribute__((address_space(3))) void*)l, 16, 0, 0);
}

__device__ __forceinline__ u16 sgn_bf16(float v) {
    return v > 0.f ? 0x3F80 : (v < 0.f ? 0xBF80 : 0);
}

// --- Prep 1 (fast path): per-row alpha = mean(|W|) AND bit-packed signs,
// layout Wbits[kword][row] (kword == K-tile index since BK=64). Bitmap = 2MB,
// L2-resident in every XCD (r4 verified: FETCH 1.16GB -> ~100MB compulsory).
__global__ void prep_wbits_kernel(const float* __restrict__ W,
                                  float* __restrict__ alpha,
                                  u64* __restrict__ Wbits) {
    const int row = blockIdx.x;                       // 0..OUT_F-1
    const int wave = threadIdx.x >> 6, lane = threadIdx.x & 63;
    const float* wr = W + (size_t)row * IN_F;
    float s = 0.f;
#pragma unroll 4
    for (int it = 0; it < 16; ++it) {
        const int kword = it * 4 + wave;              // 64 words per row
        float v = __builtin_nontemporal_load(wr + kword * 64 + lane);
        s += fabsf(v);
        u64 m = __ballot(v > 0.f);                    // 64-bit wave mask
        if (lane == 0) Wbits[(size_t)kword * OUT_F + row] = m;
    }
    for (int off = 32; off > 0; off >>= 1) s += __shfl_down(s, off);
    __shared__ float red[4];
    if (lane == 0) red[wave] = s;
    __syncthreads();
    if (threadIdx.x == 0)
        alpha[row] = (red[0] + red[1] + red[2] + red[3]) * (1.0f / IN_F);
}

// --- Prep 2: x fp32 -> bf16 (RNE), chunk-swizzled for T2 (c8 ^= row&7) ---
__global__ void convx_kernel(const float* __restrict__ X, u16* __restrict__ O,
                             int swz) {
    const size_t idx = (size_t)blockIdx.x * 256 + threadIdx.x; // 16B out chunk
    const int row = (int)(idx >> 9);                 // 512 chunks per row
    const int q = (int)idx & 511;
    const int g = q >> 3, c8 = q & 7;
    const int c8s = swz ? (c8 ^ (row & 7)) : c8;
    const f32x4* src = reinterpret_cast<const f32x4*>(
        X + (size_t)row * IN_F + g * 64 + c8s * 8);
    f32x4 a = __builtin_nontemporal_load(src);
    f32x4 b = __builtin_nontemporal_load(src + 1);
    u16x8 r;
    r[0] = f2bf(a[0]); r[1] = f2bf(a[1]); r[2] = f2bf(a[2]); r[3] = f2bf(a[3]);
    r[4] = f2bf(b[0]); r[5] = f2bf(b[1]); r[6] = f2bf(b[2]); r[7] = f2bf(b[3]);
    reinterpret_cast<u16x8*>(O)[idx] = r;
}

// ============================================================================
// Round 14: 128x256 WG tile, 4 waves (all N-split, 128x64 each), 2 WGs/CU.
// r13 post-mortem: 32x32 frag layout -> 3.35e7 bank conflicts, regressed;
// reverted to r11's 16x16 read pattern (measured 0 conflicts).
// Two fixes over r9-r11 (pinned at 490us):
// 1) LEDGER BUG FIX: r9-r11 issued stageA(t+2) BEFORE loadbits(t+1), so each
//    tile's first expand (auto-waiting on wcur = newest loads) forced a FULL
//    vmcnt drain -- the A(t+2) prefetch never rode the barrier. Now issue
//    bits(t+1) FIRST, then A(t+2): expand's auto-wait = vmcnt(4)-equivalent
//    (leaves A in flight) and the boundary is a true counted VM8.
//    Queue at tile-t boundary: [A(t+1)x4 oldest, bits(t+1)x4, A(t+2)x4] ->
//    VM8 drains exactly A(t+1) (needed next tile). Prologue [bits0,A0,A1]=12
//    -> VM4 drains bits0+A0, leaves A1. Tail t>=NT-2 -> VM0.
// 2) TWO CO-RESIDENT 4-WAVE WGs PER CU (launch_bounds(256,2), A-LDS 48KB/WG,
//    96KB/CU): independent barrier groups -- when WG0 drains/barriers, WG1's
//    waves feed the LDS+matrix pipes (m114 overlap a single barrier-synced
//    WG cannot get). Same per-CU LDS volume; per-wave tile unchanged.
// ============================================================================
__global__ __launch_bounds__(256, 2) void gemm8_kernel(
    const u16* __restrict__ Xbf, const u64* __restrict__ Wbits,
    const float* __restrict__ alpha, const float* __restrict__ bias,
    float* __restrict__ Y) {
    __shared__ u16 Alds[3][8192];   // 48KB: A triple buffer [128 rows][64 k]

    const int tid  = threadIdx.x;
    const int lane = tid & 63, wn = tid >> 6;     // 4 waves, all N-split
    const int lrow = lane & 15;

    const int wg = blockIdx.x;                    // 2048 WGs
    const int i  = wg >> 3;                       // 0..255 within XCD
    const int m0 = (((wg & 7) << 4) | (i >> 4)) << 7;   // (xcd*16+mloc)*128
    const int n0 = (i & 15) << 8;                 // n-tile * 256

    // T2 swizzled A ds_read k-offsets (u16 units) -- r11's exact pattern
    const int q0 = ((lane >> 4) << 3) ^ ((lrow & 7) << 3);
    const int q1 = q0 ^ 32;
    const int sh = (lane >> 4) << 3;              // bit offset within 32-k half

    f32x4 acc[8][4];
#pragma unroll
    for (int a = 0; a < 8; ++a)
#pragma unroll
        for (int b = 0; b < 4; ++b) acc[a][b] = (f32x4){0.f, 0.f, 0.f, 0.f};

    // stage one 64-row half of the 128-row A K-tile (2 gload_lds16 / thread)
    auto stageA = [&](int th, int half, u16* buf) {
        if (th >= NT) return;
#pragma unroll
        for (int j = 0; j < 2; ++j) {
            const int c = half * 512 + j * 256 + tid;     // 16B chunk idx
            const int row = c >> 3, c8 = c & 7;
            gload_lds16(Xbf + (size_t)(m0 + row) * IN_F + th * 64 + c8 * 8,
                        buf + c * 8);
        }
    };

    u64 wcur[4];
    auto loadbits = [&](int th) {
        if (th >= NT) return;
#pragma unroll
        for (int nf = 0; nf < 4; ++nf)
            wcur[nf] = Wbits[(size_t)th * OUT_F + n0 + wn * 64 + nf * 16 + lrow];
    };

    // expand lane's B-frag pair (kk=0,1) for one nf from its 64 sign bits.
    // bit=1 -> +1 (0x3F80), bit=0 -> -1 (0xBF80). r4/r11-verified math.
    auto expand_pair = [&](u64 w, bf16x8* dst) {
        u64 t64 = w >> sh;
        unsigned nb0 = ~(unsigned)t64;            // kk=0 byte at [7:0]
        unsigned nb1 = ~(unsigned)(t64 >> 32);    // kk=1 byte at [7:0]
        union { unsigned u[4]; bf16x8 v; } r0, r1;
#pragma unroll
        for (int e = 0; e < 4; ++e) {
            unsigned s0 = nb0 >> (2 * e), s1 = nb1 >> (2 * e);
            r0.u[e] = 0x3F803F80u | ((s0 & 1u) << 15) | ((s0 & 2u) << 30);
            r1.u[e] = 0x3F803F80u | ((s1 & 1u) << 15) | ((s1 & 2u) << 30);
        }
        dst[0] = r0.v; dst[1] = r1.v;
    };

    // rotating A-buffer pointers: pa0 = A(t), pa1 = A(t+1), pa2 = stage target
    u16* pa0 = &Alds[0][0];
    u16* pa1 = &Alds[1][0];
    u16* pa2 = &Alds[2][0];

    // ---- prologue: bits(0) FIRST, then A(0), A(1) -> VM4 drains bits0+A(0),
    // leaves A(1)x4 in flight (steady-state invariant) ----
    loadbits(0);
    stageA(0, 0, pa0); stageA(0, 1, pa0);
    stageA(1, 0, pa1); stageA(1, 1, pa1);
    VM4(); BAR();

    for (int t = 0; t < NT; ++t) {
        const u16* Ar = pa0 + lrow * 64;
        bf16x8 af0[8], af1[8];
#pragma unroll
        for (int mm = 0; mm < 8; ++mm) {          // rows mm*16 + lrow
            af0[mm] = *reinterpret_cast<const bf16x8*>(Ar + mm * 1024 + q0);
            af1[mm] = *reinterpret_cast<const bf16x8*>(Ar + mm * 1024 + q1);
        }

        bf16x8 bP[2], bQ[2];
        // --- nn=0 (expand auto-waits wcur -> drains up to bits(t), leaves
        // A(t+1) in flight: bits(t) was issued BEFORE stageA(t+1) at t-1) ---
        expand_pair(wcur[0], bP);
        __builtin_amdgcn_s_setprio(1);
#pragma unroll
        for (int mm = 0; mm < 8; ++mm) {
            acc[mm][0] = __builtin_amdgcn_mfma_f32_16x16x32_bf16(af0[mm], bP[0], acc[mm][0], 0, 0, 0);
            acc[mm][0] = __builtin_amdgcn_mfma_f32_16x16x32_bf16(af1[mm], bP[1], acc[mm][0], 0, 0, 0);
        }
        __builtin_amdgcn_s_setprio(0);
        // --- nn=1 ---
        expand_pair(wcur[1], bQ);
        __builtin_amdgcn_s_setprio(1);
#pragma unroll
        for (int mm = 0; mm < 8; ++mm) {
            acc[mm][1] = __builtin_amdgcn_mfma_f32_16x16x32_bf16(af0[mm], bQ[0], acc[mm][1], 0, 0, 0);
            acc[mm][1] = __builtin_amdgcn_mfma_f32_16x16x32_bf16(af1[mm], bQ[1], acc[mm][1], 0, 0, 0);
        }
        __builtin_amdgcn_s_setprio(0);
        // --- nn=2 ---
        expand_pair(wcur[2], bP);
        __builtin_amdgcn_s_setprio(1);
#pragma unroll
        for (int mm = 0; mm < 8; ++mm) {
            acc[mm][2] = __builtin_amdgcn_mfma_f32_16x16x32_bf16(af0[mm], bP[0], acc[mm][2], 0, 0, 0);
            acc[mm][2] = __builtin_amdgcn_mfma_f32_16x16x32_bf16(af1[mm], bP[1], acc[mm][2], 0, 0, 0);
        }
        __builtin_amdgcn_s_setprio(0);
        // --- nn=3: expand first (reads wcur[3]), THEN reload wcur=bits(t+1),
        // THEN stageA(t+2) -- ledger order bits-before-A; issue hides under
        // the nn=3 MFMA cluster ---
        expand_pair(wcur[3], bQ);
        loadbits(t + 1);
        stageA(t + 2, 0, pa2); stageA(t + 2, 1, pa2);
        __builtin_amdgcn_s_setprio(1);
#pragma unroll
        for (int mm = 0; mm < 8; ++mm) {
            acc[mm][3] = __builtin_amdgcn_mfma_f32_16x16x32_bf16(af0[mm], bQ[0], acc[mm][3], 0, 0, 0);
            acc[mm][3] = __builtin_amdgcn_mfma_f32_16x16x32_bf16(af1[mm], bQ[1], acc[mm][3], 0, 0, 0);
        }
        __builtin_amdgcn_s_setprio(0);

        // counted boundary: drain A(t+1) only (oldest 4 of 12); tail drains all
        if (t >= NT - 2) { VM0(); } else { VM8(); }
        BAR();

        u16* tp = pa0; pa0 = pa1; pa1 = pa2; pa2 = tp;
    }

    // epilogue: y = acc*alpha[col] + bias[col]; C/D: col=lane&15, row=(lane>>4)*4+r
#pragma unroll
    for (int nf = 0; nf < 4; ++nf) {
        const int col = n0 + wn * 64 + nf * 16 + lrow;
        const float al = alpha[col], bi = bias[col];
#pragma unroll
        for (int mf = 0; mf < 8; ++mf) {
            const int rbase = m0 + mf * 16 + ((lane >> 4) << 2);
#pragma unroll
            for (int r = 0; r < 4; ++r)
                __builtin_nontemporal_store(acc[mf][nf][r] * al + bi,
                    &Y[(size_t)(rbase + r) * OUT_F + col]);
        }
    }
}

// ============================================================================
// Fallback (small workspace): round-1 128x128 kernel, A reg-staged from fp32,
// bf16 Wsign unswizzled. Verified correct in round 1.
// ============================================================================
__global__ void prep_w_kernel(const float* __restrict__ W,
                              float* __restrict__ alpha,
                              u16* __restrict__ S) {
    const int row = blockIdx.x;
    const float* wr = W + (size_t)row * IN_F;
    float s = 0.f;
    for (int c = threadIdx.x; c < 512; c += 256) {
        const f32x4* src = reinterpret_cast<const f32x4*>(wr + c * 8);
        f32x4 v0 = __builtin_nontemporal_load(src);
        f32x4 v1 = __builtin_nontemporal_load(src + 1);
        s += fabsf(v0[0]) + fabsf(v0[1]) + fabsf(v0[2]) + fabsf(v0[3])
           + fabsf(v1[0]) + fabsf(v1[1]) + fabsf(v1[2]) + fabsf(v1[3]);
        u16x8 r;
        r[0] = sgn_bf16(v0[0]); r[1] = sgn_bf16(v0[1]);
        r[2] = sgn_bf16(v0[2]); r[3] = sgn_bf16(v0[3]);
        r[4] = sgn_bf16(v1[0]); r[5] = sgn_bf16(v1[1]);
        r[6] = sgn_bf16(v1[2]); r[7] = sgn_bf16(v1[3]);
        *reinterpret_cast<u16x8*>(S + (size_t)row * IN_F + c * 8) = r;
    }
    for (int off = 32; off > 0; off >>= 1) s += __shfl_down(s, off);
    __shared__ float red[4];
    const int wave = threadIdx.x >> 6, lane = threadIdx.x & 63;
    if (lane == 0) red[wave] = s;
    __syncthreads();
    if (threadIdx.x == 0)
        alpha[row] = (red[0] + red[1] + red[2] + red[3]) * (1.0f / IN_F);
}

__global__ __launch_bounds__(256) void gemm_fallback(
    const float* __restrict__ X, const u16* __restrict__ Wsign,
    const float* __restrict__ alpha, const float* __restrict__ bias,
    float* __restrict__ Y) {
    __shared__ u16 Axl[128 * 64];
    __shared__ u16 Bxl[128 * 64];

    const int tid = threadIdx.x;
    const int n0 = blockIdx.x * 128;
    const int m0 = blockIdx.y * 128;
    const int wave = tid >> 6, lane = tid & 63;
    const int wm = wave >> 1, wn = wave & 1;
    const int lrow = lane & 15;
    const int lk8 = (lane >> 4) * 8;

    f32x4 acc[4][4];
#pragma unroll
    for (int a = 0; a < 4; ++a)
#pragma unroll
        for (int b = 0; b < 4; ++b) acc[a][b] = (f32x4){0.f, 0.f, 0.f, 0.f};

    for (int kt = 0; kt < IN_F; kt += 64) {
#pragma unroll
        for (int j = 0; j < 4; ++j) {
            const int idx = j * 256 + tid;
            const int row = idx >> 3, c8 = idx & 7;
            gload_lds16(Wsign + (size_t)(n0 + row) * IN_F + kt + c8 * 8,
                        &Bxl[idx * 8]);
        }
#pragma unroll
        for (int j = 0; j < 4; ++j) {
            const int idx = j * 256 + tid;
            const int row = idx >> 3, c8 = idx & 7;
            const float* src = X + (size_t)(m0 + row) * IN_F + kt + c8 * 8;
            float4 v0 = *reinterpret_cast<const float4*>(src);
            float4 v1 = *reinterpret_cast<const float4*>(src + 4);
            u16x8 r;
            r[0] = f2bf(v0.x); r[1] = f2bf(v0.y); r[2] = f2bf(v0.z); r[3] = f2bf(v0.w);
            r[4] = f2bf(v1.x); r[5] = f2bf(v1.y); r[6] = f2bf(v1.z); r[7] = f2bf(v1.w);
            *reinterpret_cast<u16x8*>(&Axl[idx * 8]) = r;
        }
        __syncthreads();
#pragma unroll
        for (int kk = 0; kk < 2; ++kk) {
            bf16x8 af[4], bfv[4];
#pragma unroll
            for (int mf = 0; mf < 4; ++mf)
                af[mf] = *reinterpret_cast<const bf16x8*>(
                    &Axl[(wm * 64 + mf * 16 + lrow) * 64 + kk * 32 + lk8]);
#pragma unroll
            for (int nf = 0; nf < 4; ++nf)
                bfv[nf] = *reinterpret_cast<const bf16x8*>(
                    &Bxl[(wn * 64 + nf * 16 + lrow) * 64 + kk * 32 + lk8]);
#pragma unroll
            for (int mf = 0; mf < 4; ++mf)
#pragma unroll
                for (int nf = 0; nf < 4; ++nf)
                    acc[mf][nf] = __builtin_amdgcn_mfma_f32_16x16x32_bf16(
                        af[mf], bfv[nf], acc[mf][nf], 0, 0, 0);
        }
        __syncthreads();
    }
#pragma unroll
    for (int nf = 0; nf < 4; ++nf) {
        const int col = n0 + wn * 64 + nf * 16 + lrow;
        const float al = alpha[col], bi = bias[col];
#pragma unroll
        for (int mf = 0; mf < 4; ++mf) {
            const int rbase = m0 + wm * 64 + mf * 16 + (lane >> 4) * 4;
#pragma unroll
            for (int r = 0; r < 4; ++r)
                __builtin_nontemporal_store(acc[mf][nf][r] * al + bi,
                    &Y[(size_t)(rbase + r) * OUT_F + col]);
        }
    }
}

extern "C" void kernel_launch(void* const* d_in, const int* in_sizes, int n_in,
                              void* d_out, int out_size, void* d_ws, size_t ws_size,
                              hipStream_t stream) {
    const float* X    = (const float*)d_in[0];
    const float* W    = (const float*)d_in[1];
    const float* bias = (const float*)d_in[2];
    float* Y = (float*)d_out;

    char* ws = (char*)d_ws;
    float* alpha = (float*)ws;                               // 16 KB
    const size_t WBITS_OFF = 16384;
    const size_t XBF_OFF   = WBITS_OFF + (size_t)OUT_F * (IN_F / 8); // +2 MB
    const size_t need_fast = XBF_OFF + (size_t)NROWS * IN_F * 2;     // +128 MB

    if (ws_size >= need_fast) {
        u64* Wbits = (u64*)(ws + WBITS_OFF);
        u16* Xbf   = (u16*)(ws + XBF_OFF);
        prep_wbits_kernel<<<OUT_F, 256, 0, stream>>>(W, alpha, Wbits);
        convx_kernel<<<(size_t)NROWS * IN_F / 8 / 256, 256, 0, stream>>>(X, Xbf, 1);
        gemm8_kernel<<<dim3(2048), 256, 0, stream>>>(Xbf, Wbits, alpha, bias, Y);
    } else {
        u16* Wsign = (u16*)(ws + 16384);
        prep_w_kernel<<<OUT_F, 256, 0, stream>>>(W, alpha, Wsign);
        dim3 grid(OUT_F / 128, NROWS / 128);
        gemm_fallback<<<grid, 256, 0, stream>>>(X, Wsign, alpha, bias, Y);
    }
}